// Round 1
// baseline (198.347 us; speedup 1.0000x reference)
//
#include <hip/hip_runtime.h>

#define TTILE 32
#define DEC 256
#define TFULL 4096
#define CIN 32
#define HROW 164   // 64 x 164 floats, padded (164%32==4 -> conflict-free)
#define SROW 33    // 64 x 33 floats, padded
#define WS_PER_LAYER 20480  // fw 8192 + gw 8192 + pw 4096 floats
#define WS_FLOATS (8 * WS_PER_LAYER)

// ---------------- prep: transpose weights into ws ----------------
// ws per layer i (floats): [0,8192)  fw[c][o][k]   (from filt_w[i][o][c][k])
//                          [8192,16384) gw[c][o][k]
//                          [16384,20480) pw[c][o]   (from post_w[i][o][c])
__global__ __launch_bounds__(512) void wavenet_prep(
    const float* __restrict__ fw, const float* __restrict__ gw,
    const float* __restrict__ pw, float* __restrict__ ws)
{
    int idx = blockIdx.x * 512 + threadIdx.x;
    const int total = WS_FLOATS;
    const int stride = gridDim.x * 512;
    for (; idx < total; idx += stride) {
        int layer = idx / WS_PER_LAYER;
        int r = idx - layer * WS_PER_LAYER;
        float v;
        if (r < 8192) {
            int c = r >> 7, rem = r & 127, o = rem >> 1, k = r & 1;
            v = fw[((layer * 64 + o) * 64 + c) * 2 + k];
        } else if (r < 16384) {
            int r2 = r - 8192;
            int c = r2 >> 7, rem = r2 & 127, o = rem >> 1, k = r2 & 1;
            v = gw[((layer * 64 + o) * 64 + c) * 2 + k];
        } else {
            int r3 = r - 16384;
            int c = r3 >> 6, o = r3 & 63;
            v = pw[(layer * 64 + o) * 64 + c];
        }
        ws[idx] = v;
    }
}

// ---------------- fused main kernel ----------------
__global__ __launch_bounds__(512) void wavenet_main(
    const float* __restrict__ x,
    const float* __restrict__ pre_w, const float* __restrict__ pre_b,
    const float* __restrict__ filt_w, const float* __restrict__ filt_b,
    const float* __restrict__ gate_w, const float* __restrict__ gate_b,
    const float* __restrict__ post_w, const float* __restrict__ post_b,
    const float* __restrict__ d1_w, const float* __restrict__ d1_b,
    const float* __restrict__ d2_w, const float* __restrict__ d2_b,
    const float* __restrict__ ws, int use_ws,
    float* __restrict__ out)
{
    __shared__ __align__(16) float h_s[64 * HROW];   // 41984 B
    __shared__ __align__(16) float wbuf[WS_PER_LAYER]; // 81920 B
    __shared__ __align__(16) float s_s[64 * SROW];   // 8448 B

    const int tid = threadIdx.x;
    const int b = blockIdx.x >> 3;
    const int tile = blockIdx.x & 7;
    const int t0 = TFULL - DEC + tile * TTILE; // absolute start of this out-tile

    const int lane = tid & 63;
    const int wv = __builtin_amdgcn_readfirstlane(tid >> 6); // wave id, uniform
    const int q = tid >> 5;   // 0..15  (o-quad)
    const int tt = tid & 31;  // t within tile

    float accp[4] = {0.f, 0.f, 0.f, 0.f}; // skip-sum acc for o=4q+oo, t=tt

    for (int i = 0; i < 8; ++i) {
        const int dil = 1 << i;
        const int NC = TTILE + dil; // h columns: absolute t in [t0-dil, t0+32)

        // ---- weight staging ----
        if (use_ws) {
            const float4* src = (const float4*)(ws + i * WS_PER_LAYER);
            float4* dst = (float4*)wbuf;
            for (int j = tid; j < WS_PER_LAYER / 4; j += 512) dst[j] = src[j];
        } else {
            for (int m = tid; m < 8192; m += 512) {
                int c = m >> 7, rem = m & 127, o = rem >> 1, k = m & 1;
                wbuf[m] = filt_w[((i * 64 + o) * 64 + c) * 2 + k];
                wbuf[8192 + m] = gate_w[((i * 64 + o) * 64 + c) * 2 + k];
            }
            for (int m = tid; m < 4096; m += 512) {
                int c = m >> 6, o = m & 63;
                wbuf[16384 + m] = post_w[(i * 64 + o) * 64 + c];
            }
        }
        __syncthreads();

        // ---- phase 1: h[c][col] = relu(pre_w x + pre_b), col in [0,NC) ----
        {
            const float* preb = pre_b + i * 64 + wv * 8;
            const float* prew = pre_w + (i * 64 + wv * 8) * CIN; // uniform base
            for (int kk = 0; kk * 64 < NC; ++kk) {
                int col = lane + kk * 64;
                if (col < NC) {
                    int ta = t0 - dil + col;
                    const float* xp = x + b * CIN * TFULL + ta;
                    float hacc[8];
#pragma unroll
                    for (int r = 0; r < 8; ++r) hacc[r] = preb[r];
                    for (int ci = 0; ci < CIN; ++ci) {
                        float xv = xp[ci * TFULL]; // coalesced over lanes
#pragma unroll
                        for (int r = 0; r < 8; ++r)
                            hacc[r] = fmaf(prew[r * CIN + ci], xv, hacc[r]);
                    }
#pragma unroll
                    for (int r = 0; r < 8; ++r)
                        h_s[(wv * 8 + r) * HROW + col] = fmaxf(hacc[r], 0.f);
                }
            }
        }
        __syncthreads();

        // ---- phase 2: f,g,s  (o = 4q+oo, t = tt) ----
        {
            float fa[4], ga[4];
#pragma unroll
            for (int oo = 0; oo < 4; ++oo) {
                fa[oo] = filt_b[i * 64 + q * 4 + oo];
                ga[oo] = gate_b[i * 64 + q * 4 + oo];
            }
            const float4* fw4 = (const float4*)wbuf;            // [c][32]
            const float4* gw4 = (const float4*)(wbuf + 8192);   // [c][32]
            const float* hrow0 = h_s + tt;
            const float* hrow1 = h_s + tt + dil;
#pragma unroll 4
            for (int c = 0; c < 64; ++c) {
                float4 f0 = fw4[c * 32 + q * 2];
                float4 f1 = fw4[c * 32 + q * 2 + 1];
                float4 g0 = gw4[c * 32 + q * 2];
                float4 g1 = gw4[c * 32 + q * 2 + 1];
                float h0 = hrow0[c * HROW]; // tap w[...,0] * x[t-dil]
                float h1 = hrow1[c * HROW]; // tap w[...,1] * x[t]
                fa[0] = fmaf(f0.x, h0, fmaf(f0.y, h1, fa[0]));
                fa[1] = fmaf(f0.z, h0, fmaf(f0.w, h1, fa[1]));
                fa[2] = fmaf(f1.x, h0, fmaf(f1.y, h1, fa[2]));
                fa[3] = fmaf(f1.z, h0, fmaf(f1.w, h1, fa[3]));
                ga[0] = fmaf(g0.x, h0, fmaf(g0.y, h1, ga[0]));
                ga[1] = fmaf(g0.z, h0, fmaf(g0.w, h1, ga[1]));
                ga[2] = fmaf(g1.x, h0, fmaf(g1.y, h1, ga[2]));
                ga[3] = fmaf(g1.z, h0, fmaf(g1.w, h1, ga[3]));
            }
#pragma unroll
            for (int oo = 0; oo < 4; ++oo) {
                float sv = tanhf(fa[oo]) * fmaxf(ga[oo], 0.f);
                s_s[(q * 4 + oo) * SROW + tt] = sv;
            }
        }
        __syncthreads();

        // ---- phase 3: post conv, accumulate skip in registers ----
        {
            float pa[4];
#pragma unroll
            for (int oo = 0; oo < 4; ++oo) pa[oo] = post_b[i * 64 + q * 4 + oo];
            const float4* pw4 = (const float4*)(wbuf + 16384); // [c][16]
#pragma unroll 4
            for (int c = 0; c < 64; ++c) {
                float4 pv = pw4[c * 16 + q];
                float sv = s_s[c * SROW + tt];
                pa[0] = fmaf(pv.x, sv, pa[0]);
                pa[1] = fmaf(pv.y, sv, pa[1]);
                pa[2] = fmaf(pv.z, sv, pa[2]);
                pa[3] = fmaf(pv.w, sv, pa[3]);
            }
#pragma unroll
            for (int oo = 0; oo < 4; ++oo) accp[oo] += fmaxf(pa[oo], 0.f);
        }
        __syncthreads(); // wbuf about to be overwritten by next layer
    }

    // ---- write acc to LDS as [c][t] ----
#pragma unroll
    for (int oo = 0; oo < 4; ++oo) s_s[(q * 4 + oo) * SROW + tt] = accp[oo];
    __syncthreads();

    // ---- phase 4: dense head 64 -> 128 -> 1 ----
    {
        const int pg = tid >> 5; // 16 groups x 8 p
        float partial = 0.f;
#pragma unroll
        for (int pp = 0; pp < 8; ++pp) {
            const int p = pg * 8 + pp;
            float z = d1_b[p];
            const float4* w4 = (const float4*)(d1_w + p * 64);
#pragma unroll 4
            for (int c4 = 0; c4 < 16; ++c4) {
                float4 w = w4[c4];
                z = fmaf(w.x, s_s[(c4 * 4 + 0) * SROW + tt], z);
                z = fmaf(w.y, s_s[(c4 * 4 + 1) * SROW + tt], z);
                z = fmaf(w.z, s_s[(c4 * 4 + 2) * SROW + tt], z);
                z = fmaf(w.w, s_s[(c4 * 4 + 3) * SROW + tt], z);
            }
            partial = fmaf(d2_w[p], fmaxf(z, 0.f), partial);
        }
        h_s[pg * 32 + tt] = partial;
    }
    __syncthreads();
    if (tid < 32) {
        float sum = d2_b[0];
#pragma unroll
        for (int g = 0; g < 16; ++g) sum += h_s[g * 32 + tid];
        out[b * DEC + tile * TTILE + tid] = fmaxf(sum, 0.f);
    }
}

extern "C" void kernel_launch(void* const* d_in, const int* in_sizes, int n_in,
                              void* d_out, int out_size, void* d_ws, size_t ws_size,
                              hipStream_t stream)
{
    const float* x      = (const float*)d_in[0];
    const float* pre_w  = (const float*)d_in[1];
    const float* pre_b  = (const float*)d_in[2];
    const float* filt_w = (const float*)d_in[3];
    const float* filt_b = (const float*)d_in[4];
    const float* gate_w = (const float*)d_in[5];
    const float* gate_b = (const float*)d_in[6];
    const float* post_w = (const float*)d_in[7];
    const float* post_b = (const float*)d_in[8];
    const float* d1_w   = (const float*)d_in[9];
    const float* d1_b   = (const float*)d_in[10];
    const float* d2_w   = (const float*)d_in[11];
    const float* d2_b   = (const float*)d_in[12];
    float* out = (float*)d_out;
    float* ws  = (float*)d_ws;

    const int use_ws = (ws_size >= (size_t)WS_FLOATS * sizeof(float)) ? 1 : 0;
    if (use_ws) {
        wavenet_prep<<<160, 512, 0, stream>>>(filt_w, gate_w, post_w, ws);
    }
    wavenet_main<<<256, 512, 0, stream>>>(
        x, pre_w, pre_b, filt_w, filt_b, gate_w, gate_b, post_w, post_b,
        d1_w, d1_b, d2_w, d2_b, ws, use_ws, out);
}